// Round 2
// baseline (158.492 us; speedup 1.0000x reference)
//
#include <hip/hip_runtime.h>
#include <hip/hip_bf16.h>
#include <cmath>

#define B_   4
#define NT_  2048
#define G_   4096
#define DZ_  128
#define TILE_ (64 * 72)   // one z-tile: 64 z-rows x (64 data + 8 pad) ushorts

typedef __attribute__((ext_vector_type(8))) short bf16x8;
typedef __attribute__((ext_vector_type(4))) float f32x4;

__device__ __forceinline__ float softplus_f(float x) {
    return fmaxf(x, 0.0f) + log1pf(expf(-fabsf(x)));
}

// z_grid (B,G,DZ) fp32 -> Zt (B,DZ,G) bf16 (RNE)
__global__ __launch_bounds__(256, 1)
void transpose_z(const float* __restrict__ z, unsigned short* __restrict__ zt)
{
    __shared__ unsigned short tile[64][66];
    const int bx = blockIdx.x;                // 4b * 64gt * 2zt = 512
    const int zti = bx & 1;
    const int gt  = (bx >> 1) & 63;
    const int b   = bx >> 7;
    const int g0 = gt * 64, z0 = zti * 64;
    const int tid = threadIdx.x;
    const int zl = tid & 63, gl = tid >> 6;
    #pragma unroll
    for (int i = 0; i < 16; ++i) {
        const int g = gl + i * 4;
        const float v = z[(size_t)(b * G_ + g0 + g) * DZ_ + z0 + zl];
        unsigned int u = __float_as_uint(v);
        u = u + 0x7FFFu + ((u >> 16) & 1u);   // RNE to bf16
        tile[g][zl] = (unsigned short)(u >> 16);
    }
    __syncthreads();
    const int gl2 = tid & 63, zl2 = tid >> 6;
    #pragma unroll
    for (int i = 0; i < 16; ++i) {
        const int zz = zl2 + i * 4;
        zt[(size_t)(b * DZ_ + z0 + zz) * G_ + g0 + gl2] = tile[gl2][zz];
    }
}

// Block: (b, 32 t, 64 z). 8 waves = (mt in {0,1}) x (kh in 0..3 k-split).
// Wave: 16 t-rows (one m-tile), all 4 n-tiles, 16 of 64 k-chunks.
// Weights computed in-register in MFMA A-layout; zero redundancy.
__global__ __launch_bounds__(512, 4)
void setconv_main(const float* __restrict__ xt,
                  const float* __restrict__ xg,
                  const float* __restrict__ lsp,
                  const unsigned short* __restrict__ Zt,
                  float* __restrict__ out)
{
    __shared__ unsigned short ldsZ[4 * TILE_];   // 36864 B; reused for reduction

    const int bx   = blockIdx.x;                 // 512 = (b*2+zh)*64 + tt
    const int tt   = bx & 63;
    const int zh   = (bx >> 6) & 1;
    const int b    = bx >> 7;
    const int tid  = threadIdx.x;
    const int w    = tid >> 6;
    const int lane = tid & 63;
    const int mt   = w & 1;
    const int kh   = w >> 1;                     // 0..3
    const int l15  = lane & 15;
    const int quad = lane >> 4;

    const int t0 = tt * 32;
    const int z0 = zh * 64;

    // c[d][k] = -0.5*log2(e)/ls_dk^2  (exp(-0.5*s) == exp2(sum q_d * c_dk))
    float c00, c01, c10, c11;
    {
        const float h = -0.72134752f;            // -0.5*log2(e)
        float p, ls;
        p = lsp[0]; ls = 1e-5f + softplus_f(p); c00 = h / (ls * ls);
        p = lsp[1]; ls = 1e-5f + softplus_f(p); c01 = h / (ls * ls);
        p = lsp[2]; ls = 1e-5f + softplus_f(p); c10 = h / (ls * ls);
        p = lsp[3]; ls = 1e-5f + softplus_f(p); c11 = h / (ls * ls);
    }

    const int trow = t0 + mt * 16 + l15;         // A-frag row m = lane&15
    const float xt0 = xt[(size_t)(b * NT_ + trow) * 2 + 0];
    const float xt1 = xt[(size_t)(b * NT_ + trow) * 2 + 1];

    f32x4 acc[2][4];
    #pragma unroll
    for (int k = 0; k < 2; ++k)
        #pragma unroll
        for (int n = 0; n < 4; ++n) acc[k][n] = (f32x4)0.0f;

    // Staging: wave w stages tile (w>>1), rows mt*32 + r*8 + (lane>>3)
    const int srow = mt * 32 + (lane >> 3);
    const int scol = (lane & 7) * 8;             // ushort col (16B/lane)
    const unsigned short* sb = Zt + (size_t)(b * DZ_ + z0 + srow) * G_
                               + kh * 16 * 64 + scol;
    unsigned short* ldst = &ldsZ[kh * TILE_ + srow * 72 + scol];

    uint4 p[4];
    #pragma unroll
    for (int r = 0; r < 4; ++r)
        p[r] = *(const uint4*)(sb + (size_t)r * 8 * G_);

    const unsigned short* myt = &ldsZ[kh * TILE_];
    const float* xgb = xg + (size_t)b * G_ * 2;

    for (int i = 0; i < 16; ++i) {
        __syncthreads();                         // prev tile fully consumed
        #pragma unroll
        for (int r = 0; r < 4; ++r)
            *(uint4*)(ldst + r * 8 * 72) = p[r];
        __syncthreads();
        if (i < 15) {
            #pragma unroll
            for (int r = 0; r < 4; ++r)
                p[r] = *(const uint4*)(sb + (size_t)r * 8 * G_ + (i + 1) * 64);
        }
        const int gbase = (kh * 16 + i) * 64;
        #pragma unroll
        for (int s = 0; s < 2; ++s) {
            bf16x8 bz[4];
            #pragma unroll
            for (int nt = 0; nt < 4; ++nt) {
                const int idx = (nt * 16 + l15) * 72 + s * 32 + quad * 8;
                bz[nt] = *(const bf16x8*)(&ldsZ[kh * TILE_ + idx]);
            }
            const float* xp = xgb + (size_t)(gbase + s * 32 + quad * 8) * 2;
            const float4 xv0 = *(const float4*)(xp + 0);
            const float4 xv1 = *(const float4*)(xp + 4);
            const float4 xv2 = *(const float4*)(xp + 8);
            const float4 xv3 = *(const float4*)(xp + 12);
            float gx[8], gy[8];
            gx[0]=xv0.x; gy[0]=xv0.y; gx[1]=xv0.z; gy[1]=xv0.w;
            gx[2]=xv1.x; gy[2]=xv1.y; gx[3]=xv1.z; gy[3]=xv1.w;
            gx[4]=xv2.x; gy[4]=xv2.y; gx[5]=xv2.z; gy[5]=xv2.w;
            gx[6]=xv3.x; gy[6]=xv3.y; gx[7]=xv3.z; gy[7]=xv3.w;
            unsigned int w0b[8], w1b[8];
            #pragma unroll
            for (int j = 0; j < 8; ++j) {
                const float d0 = xt0 - gx[j];
                const float d1 = xt1 - gy[j];
                const float q0 = d0 * d0;
                const float q1 = d1 * d1;
                const float e0 = fmaf(q1, c10, q0 * c00);
                const float e1 = fmaf(q1, c11, q0 * c01);
                w0b[j] = __float_as_uint(__builtin_amdgcn_exp2f(e0));
                w1b[j] = __float_as_uint(__builtin_amdgcn_exp2f(e1));
            }
            union { bf16x8 v; unsigned int u[4]; } a0, a1;
            #pragma unroll
            for (int h = 0; h < 4; ++h) {
                a0.u[h] = __builtin_amdgcn_perm(w0b[2*h+1], w0b[2*h], 0x07060302u);
                a1.u[h] = __builtin_amdgcn_perm(w1b[2*h+1], w1b[2*h], 0x07060302u);
            }
            #pragma unroll
            for (int nt = 0; nt < 4; ++nt) {
                acc[0][nt] = __builtin_amdgcn_mfma_f32_16x16x32_bf16(a0.v, bz[nt], acc[0][nt], 0, 0, 0);
                acc[1][nt] = __builtin_amdgcn_mfma_f32_16x16x32_bf16(a1.v, bz[nt], acc[1][nt], 0, 0, 0);
            }
        }
    }

    // ---- k-reduction across kh waves (2 rounds), then kh==0 stores ----
    float* red = (float*)ldsZ;                   // stride-33 rows: conflict-free
    __syncthreads();
    if (kh >= 2) {
        float* base = red + ((kh - 2) * 2 + mt) * 2112 + lane * 33;
        #pragma unroll
        for (int k = 0; k < 2; ++k)
            #pragma unroll
            for (int nt = 0; nt < 4; ++nt)
                #pragma unroll
                for (int r = 0; r < 4; ++r)
                    base[k * 16 + nt * 4 + r] = acc[k][nt][r];
    }
    __syncthreads();
    if (kh < 2) {
        const float* base = red + (kh * 2 + mt) * 2112 + lane * 33;
        #pragma unroll
        for (int k = 0; k < 2; ++k)
            #pragma unroll
            for (int nt = 0; nt < 4; ++nt)
                #pragma unroll
                for (int r = 0; r < 4; ++r)
                    acc[k][nt][r] += base[k * 16 + nt * 4 + r];
    }
    __syncthreads();
    if (kh == 1) {
        float* base = red + mt * 2112 + lane * 33;
        #pragma unroll
        for (int k = 0; k < 2; ++k)
            #pragma unroll
            for (int nt = 0; nt < 4; ++nt)
                #pragma unroll
                for (int r = 0; r < 4; ++r)
                    base[k * 16 + nt * 4 + r] = acc[k][nt][r];
    }
    __syncthreads();
    if (kh == 0) {
        const float* base = red + mt * 2112 + lane * 33;
        #pragma unroll
        for (int k = 0; k < 2; ++k)
            #pragma unroll
            for (int nt = 0; nt < 4; ++nt)
                #pragma unroll
                for (int r = 0; r < 4; ++r)
                    acc[k][nt][r] += base[k * 16 + nt * 4 + r];

        const int trb = t0 + mt * 16 + quad * 4;
        #pragma unroll
        for (int nt = 0; nt < 4; ++nt) {
            const int zz = z0 + nt * 16 + l15;
            #pragma unroll
            for (int r = 0; r < 4; ++r) {
                float2 v = make_float2(acc[0][nt][r], acc[1][nt][r]);
                *(float2*)(out + (size_t)(b * NT_ + trb + r) * (DZ_ * 2) + zz * 2) = v;
            }
        }
    }
}

extern "C" void kernel_launch(void* const* d_in, const int* in_sizes, int n_in,
                              void* d_out, int out_size, void* d_ws, size_t ws_size,
                              hipStream_t stream)
{
    const float* x_grid = (const float*)d_in[0];   // (4,64,64,2)
    const float* z_grid = (const float*)d_in[1];   // (4,64,64,128)
    const float* xt     = (const float*)d_in[2];   // (4,2048,2)
    const float* lsp    = (const float*)d_in[3];   // (2,2)
    float* out = (float*)d_out;                    // (4,2048,256) fp32
    unsigned short* Zt = (unsigned short*)d_ws;    // (4,128,4096) bf16 = 4 MB

    hipLaunchKernelGGL(transpose_z, dim3(512), dim3(256), 0, stream, z_grid, Zt);
    hipLaunchKernelGGL(setconv_main, dim3(512), dim3(512), 0, stream,
                       xt, x_grid, lsp, Zt, out);
}

// Round 3
// 114.780 us; speedup vs baseline: 1.3808x; 1.3808x over previous
//
#include <hip/hip_runtime.h>
#include <hip/hip_bf16.h>
#include <cmath>

#define B_   4
#define NT_  2048
#define G_   4096
#define DZ_  128

typedef __attribute__((ext_vector_type(8))) short bf16x8;
typedef __attribute__((ext_vector_type(4))) float f32x4;

__device__ __forceinline__ float softplus_f(float x) {
    return fmaxf(x, 0.0f) + log1pf(expf(-fabsf(x)));
}

// async 16B global -> LDS (lane i lands at ldst + 16*i)
__device__ __forceinline__ void gl2lds16(const void* gsrc, void* ldst) {
    __builtin_amdgcn_global_load_lds(
        (const __attribute__((address_space(1))) unsigned int*)gsrc,
        (__attribute__((address_space(3))) unsigned int*)ldst, 16, 0, 0);
}

// z_grid (B,G,DZ) fp32 -> Zt (B,DZ,G) bf16 (RNE), packed-uint stores
__global__ __launch_bounds__(256, 1)
void transpose_z(const float* __restrict__ z, unsigned short* __restrict__ zt)
{
    __shared__ unsigned short tile[64][66];
    const int bx = blockIdx.x;                // 4b * 64gt * 2zt = 512
    const int zti = bx & 1;
    const int gt  = (bx >> 1) & 63;
    const int b   = bx >> 7;
    const int g0 = gt * 64, z0 = zti * 64;
    const int tid = threadIdx.x;
    const int zl = tid & 63, gl = tid >> 6;
    #pragma unroll
    for (int i = 0; i < 16; ++i) {
        const int g = gl + i * 4;
        const float v = z[(size_t)(b * G_ + g0 + g) * DZ_ + z0 + zl];
        unsigned int u = __float_as_uint(v);
        u = u + 0x7FFFu + ((u >> 16) & 1u);   // RNE to bf16
        tile[g][zl] = (unsigned short)(u >> 16);
    }
    __syncthreads();
    // store: 2 consecutive g per lane -> one uint
    const int gp = (tid & 31) * 2, zi = tid >> 5;   // zi 0..7
    #pragma unroll
    for (int i = 0; i < 8; ++i) {
        const int zz = zi + i * 8;
        const unsigned int lo = tile[gp][zz], hi = tile[gp + 1][zz];
        *(unsigned int*)(zt + (size_t)(b * DZ_ + z0 + zz) * G_ + g0 + gp)
            = lo | (hi << 16);
    }
}

// Block: (b, 32 t, 64 z). 8 waves = (mt in {0,1}) x (kh 0..3 k-split).
// Async global_load_lds staging, XOR-swizzled, double-buffered, 1 barrier/chunk.
__global__ __launch_bounds__(512, 4)
void setconv_main(const float* __restrict__ xt,
                  const float* __restrict__ xg,
                  const float* __restrict__ lsp,
                  const unsigned short* __restrict__ Zt,
                  float* __restrict__ out)
{
    __shared__ unsigned short ldsZ[32768];       // 4 kh x 2 buf x (64r x 64c) = 64 KB

    const int bx   = blockIdx.x;                 // 512 = (b*2+zh)*64 + tt
    const int tt   = bx & 63;
    const int zh   = (bx >> 6) & 1;
    const int b    = bx >> 7;
    const int tid  = threadIdx.x;
    const int w    = tid >> 6;
    const int lane = tid & 63;
    const int mt   = w & 1;
    const int kh   = w >> 1;                     // 0..3
    const int l15  = lane & 15;
    const int quad = lane >> 4;

    const int t0 = tt * 32;
    const int z0 = zh * 64;

    float c00, c01, c10, c11;
    {
        const float h = -0.72134752f;            // -0.5*log2(e)
        float p, ls;
        p = lsp[0]; ls = 1e-5f + softplus_f(p); c00 = h / (ls * ls);
        p = lsp[1]; ls = 1e-5f + softplus_f(p); c01 = h / (ls * ls);
        p = lsp[2]; ls = 1e-5f + softplus_f(p); c10 = h / (ls * ls);
        p = lsp[3]; ls = 1e-5f + softplus_f(p); c11 = h / (ls * ls);
    }

    const int trow = t0 + mt * 16 + l15;         // A-frag row m = lane&15
    const float xt0 = xt[(size_t)(b * NT_ + trow) * 2 + 0];
    const float xt1 = xt[(size_t)(b * NT_ + trow) * 2 + 1];

    f32x4 acc[2][4];
    #pragma unroll
    for (int k = 0; k < 2; ++k)
        #pragma unroll
        for (int n = 0; n < 4; ++n) acc[k][n] = (f32x4)0.0f;

    // staging: wave (kh,mt) stages rows mt*32..+31 of kh's 64x64 tile
    const int r8 = lane >> 3, c8 = lane & 7;
    const int gc = c8 ^ r8;                      // swizzled global chunk
    const unsigned short* gsrc = Zt + (size_t)(b * DZ_ + z0 + mt * 32 + r8) * G_
                                 + (size_t)kh * 1024 + gc * 8;
    unsigned short* const myTile = &ldsZ[kh * 8192];
    const int swz = l15 & 7;

    // prologue: stage chunk 0 into buf 0
    {
        unsigned short* dst = myTile + mt * 2048;
        #pragma unroll
        for (int r = 0; r < 4; ++r)
            gl2lds16(gsrc + (size_t)r * 8 * G_, dst + r * 512);
    }

    const float* xgb = xg + (size_t)b * G_ * 2;

    for (int ch = 0; ch < 16; ++ch) {
        __syncthreads();                         // drains async loads for ch
        if (ch < 15) {                           // stage ch+1 into other buf
            unsigned short* dst = myTile + ((ch + 1) & 1) * 4096 + mt * 2048;
            const unsigned short* src = gsrc + (size_t)(ch + 1) * 64;
            #pragma unroll
            for (int r = 0; r < 4; ++r)
                gl2lds16(src + (size_t)r * 8 * G_, dst + r * 512);
        }
        const unsigned short* tb = myTile + (ch & 1) * 4096;
        const int gbase = (kh * 16 + ch) * 64;
        #pragma unroll
        for (int s = 0; s < 2; ++s) {
            bf16x8 bz[4];
            #pragma unroll
            for (int nt = 0; nt < 4; ++nt) {
                const int idx = (nt * 16 + l15) * 64 + (((s * 4 + quad) ^ swz) * 8);
                bz[nt] = *(const bf16x8*)(tb + idx);
            }
            const float* xp = xgb + (size_t)(gbase + s * 32 + quad * 8) * 2;
            const float4 xv0 = *(const float4*)(xp + 0);
            const float4 xv1 = *(const float4*)(xp + 4);
            const float4 xv2 = *(const float4*)(xp + 8);
            const float4 xv3 = *(const float4*)(xp + 12);
            float gx[8], gy[8];
            gx[0]=xv0.x; gy[0]=xv0.y; gx[1]=xv0.z; gy[1]=xv0.w;
            gx[2]=xv1.x; gy[2]=xv1.y; gx[3]=xv1.z; gy[3]=xv1.w;
            gx[4]=xv2.x; gy[4]=xv2.y; gx[5]=xv2.z; gy[5]=xv2.w;
            gx[6]=xv3.x; gy[6]=xv3.y; gx[7]=xv3.z; gy[7]=xv3.w;
            unsigned int w0b[8], w1b[8];
            #pragma unroll
            for (int j = 0; j < 8; ++j) {
                const float d0 = xt0 - gx[j];
                const float d1 = xt1 - gy[j];
                const float q0 = d0 * d0;
                const float q1 = d1 * d1;
                const float e0 = fmaf(q1, c10, q0 * c00);
                const float e1 = fmaf(q1, c11, q0 * c01);
                w0b[j] = __float_as_uint(__builtin_amdgcn_exp2f(e0));
                w1b[j] = __float_as_uint(__builtin_amdgcn_exp2f(e1));
            }
            union { bf16x8 v; unsigned int u[4]; } a0, a1;
            #pragma unroll
            for (int h = 0; h < 4; ++h) {
                a0.u[h] = __builtin_amdgcn_perm(w0b[2*h+1], w0b[2*h], 0x07060302u);
                a1.u[h] = __builtin_amdgcn_perm(w1b[2*h+1], w1b[2*h], 0x07060302u);
            }
            #pragma unroll
            for (int nt = 0; nt < 4; ++nt) {
                acc[0][nt] = __builtin_amdgcn_mfma_f32_16x16x32_bf16(a0.v, bz[nt], acc[0][nt], 0, 0, 0);
                acc[1][nt] = __builtin_amdgcn_mfma_f32_16x16x32_bf16(a1.v, bz[nt], acc[1][nt], 0, 0, 0);
            }
        }
    }

    // ---- k-reduction across kh waves (2 rounds), then kh==0 stores ----
    float* red = (float*)ldsZ;                   // stride-33 rows: conflict-free
    __syncthreads();
    if (kh >= 2) {
        float* base = red + ((kh - 2) * 2 + mt) * 2112 + lane * 33;
        #pragma unroll
        for (int k = 0; k < 2; ++k)
            #pragma unroll
            for (int nt = 0; nt < 4; ++nt)
                #pragma unroll
                for (int r = 0; r < 4; ++r)
                    base[k * 16 + nt * 4 + r] = acc[k][nt][r];
    }
    __syncthreads();
    if (kh < 2) {
        const float* base = red + (kh * 2 + mt) * 2112 + lane * 33;
        #pragma unroll
        for (int k = 0; k < 2; ++k)
            #pragma unroll
            for (int nt = 0; nt < 4; ++nt)
                #pragma unroll
                for (int r = 0; r < 4; ++r)
                    acc[k][nt][r] += base[k * 16 + nt * 4 + r];
    }
    __syncthreads();
    if (kh == 1) {
        float* base = red + mt * 2112 + lane * 33;
        #pragma unroll
        for (int k = 0; k < 2; ++k)
            #pragma unroll
            for (int nt = 0; nt < 4; ++nt)
                #pragma unroll
                for (int r = 0; r < 4; ++r)
                    base[k * 16 + nt * 4 + r] = acc[k][nt][r];
    }
    __syncthreads();
    if (kh == 0) {
        const float* base = red + mt * 2112 + lane * 33;
        #pragma unroll
        for (int k = 0; k < 2; ++k)
            #pragma unroll
            for (int nt = 0; nt < 4; ++nt)
                #pragma unroll
                for (int r = 0; r < 4; ++r)
                    acc[k][nt][r] += base[k * 16 + nt * 4 + r];

        const int trb = t0 + mt * 16 + quad * 4;
        #pragma unroll
        for (int nt = 0; nt < 4; ++nt) {
            const int zz = z0 + nt * 16 + l15;
            #pragma unroll
            for (int r = 0; r < 4; ++r) {
                float2 v = make_float2(acc[0][nt][r], acc[1][nt][r]);
                *(float2*)(out + (size_t)(b * NT_ + trb + r) * (DZ_ * 2) + zz * 2) = v;
            }
        }
    }
}

extern "C" void kernel_launch(void* const* d_in, const int* in_sizes, int n_in,
                              void* d_out, int out_size, void* d_ws, size_t ws_size,
                              hipStream_t stream)
{
    const float* x_grid = (const float*)d_in[0];   // (4,64,64,2)
    const float* z_grid = (const float*)d_in[1];   // (4,64,64,128)
    const float* xt     = (const float*)d_in[2];   // (4,2048,2)
    const float* lsp    = (const float*)d_in[3];   // (2,2)
    float* out = (float*)d_out;                    // (4,2048,256) fp32
    unsigned short* Zt = (unsigned short*)d_ws;    // (4,128,4096) bf16 = 4 MB

    hipLaunchKernelGGL(transpose_z, dim3(512), dim3(256), 0, stream, z_grid, Zt);
    hipLaunchKernelGGL(setconv_main, dim3(512), dim3(512), 0, stream,
                       xt, x_grid, lsp, Zt, out);
}